// Round 7
// baseline (161.026 us; speedup 1.0000x reference)
//
#include <hip/hip_runtime.h>

#define CCH   128
#define NC2   64        // channel pairs
#define SV    24
#define NVOX  13824     // 24^3
#define SH    728       // padded h-stride (cells)
#define SW    28        // padded w-stride (cells)
#define PVOL  18928     // 26 * 728 padded volume (cells)

// pad-volume cell index of interior voxel lin (d-slot offset +2 keeps parity)
__device__ __forceinline__ int pad_base(int lin) {
    const int h = lin / 576;
    const int r = lin - h * 576;
    const int w = r / 24;
    const int d = r - w * 24;
    return (h + 1) * SH + (w + 1) * SW + d + 2;
}
// window-slot shift offset (cells), s = i*9 + j*3 + l
__device__ __forceinline__ int slot_off(int s) {
    return (s / 9 - 1) * SH + ((s / 3) % 3 - 1) * SW + (s % 3 - 1);
}

// ---------------------------------------------------------------------------
// proj: C[o][vox] = sum_c W[o][c] X[c][vox] + b[o], for m = blockIdx.y in
// {0:q, 1:k, 2:v}; y==3 blocks fill pad cells with bias + compute biasW.
// Tile 128 o x 64 vox, K-tile 32. Outputs channel-pair interleaved:
//   q -> qI[c2][13824][2],  k/v -> kI/vI[c2][PVOL][2]  (all fp32).
// Grid (216, 4), block 256.
// ---------------------------------------------------------------------------
__global__ __launch_bounds__(256) void proj_kernel(
    const float* __restrict__ x,
    const float* __restrict__ wq, const float* __restrict__ bq,
    const float* __restrict__ wk, const float* __restrict__ bk,
    const float* __restrict__ wv, const float* __restrict__ bv,
    const float* __restrict__ relh, const float* __restrict__ relw,
    const float* __restrict__ reld,
    float* __restrict__ qI, float* __restrict__ kI, float* __restrict__ vI,
    float* __restrict__ biasW)
{
    const int m   = blockIdx.y;
    const int tid = threadIdx.x;

    if (m == 3) {                       // ---- pad fill + biasW ----
        if (blockIdx.x == 0 && tid < 27) {
            const int i = tid / 9, j = (tid / 3) % 3, l = tid % 3;
            float s = 0.f;
            for (int c = 0; c < 64; ++c)
                s += relh[c * 3 + i] + relw[c * 3 + j] + reld[c * 3 + l];
            biasW[tid] = s;
        }
        const int g = blockIdx.x * 256 + tid;
        if (g < PVOL) {
            const int ph = g / SH;
            const int r  = g - ph * SH;
            const int pw = r / SW;
            const int pd = r - pw * SW;
            const bool interior = ((unsigned)(ph - 1) < 24u) &&
                                  ((unsigned)(pw - 1) < 24u) &&
                                  ((unsigned)(pd - 2) < 24u);
            if (!interior) {
                float2* kp2 = (float2*)kI;
                float2* vp2 = (float2*)vI;
                for (int c2 = 0; c2 < NC2; ++c2) {
                    float2 kv = {bk[2 * c2], bk[2 * c2 + 1]};
                    float2 vv = {bv[2 * c2], bv[2 * c2 + 1]};
                    kp2[(size_t)c2 * PVOL + g] = kv;
                    vp2[(size_t)c2 * PVOL + g] = vv;
                }
            }
        }
        return;
    }

    const float* __restrict__ w = (m == 0) ? wq : (m == 1) ? wk : wv;
    const float* __restrict__ b = (m == 0) ? bq : (m == 1) ? bk : bv;

    __shared__ float Xs[32][68];        // stride 68: conflict-free, 16B rows
    __shared__ float Ws[32][132];       // transposed W, stride 132

    const int vox0 = blockIdx.x * 64;
    const int o0   = (tid >> 4) * 8;    // 8 outputs / thread
    const int v0   = (tid & 15) * 4;    // 4 voxels / thread

    const int xr    = tid >> 3;         // X stage: row 0..31
    const int xc4   = (tid & 7) * 8;    //          col 0,8,..,56
    const int o_r   = tid >> 1;         // W stage: o-row 0..127
    const int c_off = (tid & 1) * 16;   //          c-offset 0/16

    float acc[8][4] = {{0.f}};

    for (int k0 = 0; k0 < CCH; k0 += 32) {
        const float* xs = x + (size_t)(k0 + xr) * NVOX + vox0 + xc4;
        const float4 a0 = *(const float4*)xs;
        const float4 a1 = *(const float4*)(xs + 4);
        const float* wsrc = w + o_r * CCH + k0 + c_off;
        const float4 b0 = *(const float4*)wsrc;
        const float4 b1 = *(const float4*)(wsrc + 4);
        const float4 b2 = *(const float4*)(wsrc + 8);
        const float4 b3 = *(const float4*)(wsrc + 12);

        __syncthreads();
        *(float4*)&Xs[xr][xc4]     = a0;
        *(float4*)&Xs[xr][xc4 + 4] = a1;
        Ws[c_off +  0][o_r] = b0.x; Ws[c_off +  1][o_r] = b0.y;
        Ws[c_off +  2][o_r] = b0.z; Ws[c_off +  3][o_r] = b0.w;
        Ws[c_off +  4][o_r] = b1.x; Ws[c_off +  5][o_r] = b1.y;
        Ws[c_off +  6][o_r] = b1.z; Ws[c_off +  7][o_r] = b1.w;
        Ws[c_off +  8][o_r] = b2.x; Ws[c_off +  9][o_r] = b2.y;
        Ws[c_off + 10][o_r] = b2.z; Ws[c_off + 11][o_r] = b2.w;
        Ws[c_off + 12][o_r] = b3.x; Ws[c_off + 13][o_r] = b3.y;
        Ws[c_off + 14][o_r] = b3.z; Ws[c_off + 15][o_r] = b3.w;
        __syncthreads();

#pragma unroll
        for (int k = 0; k < 32; ++k) {
            const float4 wA = *(const float4*)&Ws[k][o0];
            const float4 wB = *(const float4*)&Ws[k][o0 + 4];
            const float4 xv = *(const float4*)&Xs[k][v0];
            const float wr[8] = {wA.x, wA.y, wA.z, wA.w,
                                 wB.x, wB.y, wB.z, wB.w};
            const float xr4[4] = {xv.x, xv.y, xv.z, xv.w};
#pragma unroll
            for (int i = 0; i < 8; ++i)
#pragma unroll
                for (int v = 0; v < 4; ++v)
                    acc[i][v] = fmaf(wr[i], xr4[v], acc[i][v]);
        }
    }

    float br[8];
    *(float4*)br       = *(const float4*)(b + o0);
    *(float4*)(br + 4) = *(const float4*)(b + o0 + 4);
    float r[8][4];
#pragma unroll
    for (int i = 0; i < 8; ++i)
#pragma unroll
        for (int v = 0; v < 4; ++v) r[i][v] = acc[i][v] + br[i];

    const int lin0 = vox0 + v0;
    if (m == 0) {
        float2* q2 = (float2*)qI;
#pragma unroll
        for (int t = 0; t < 4; ++t) {
            const int c2 = (o0 >> 1) + t;
#pragma unroll
            for (int vp = 0; vp < 2; ++vp) {
                const int v = vp * 2;
                float4 st = {r[2 * t][v],     r[2 * t + 1][v],
                             r[2 * t][v + 1], r[2 * t + 1][v + 1]};
                *(float4*)&q2[(size_t)c2 * NVOX + lin0 + v] = st;
            }
        }
    } else {
        float2* p2 = (float2*)((m == 1) ? kI : vI);
        const int pb = pad_base(lin0);  // 4 voxels are contiguous in pad vol
#pragma unroll
        for (int t = 0; t < 4; ++t) {
            const int c2 = (o0 >> 1) + t;
#pragma unroll
            for (int vp = 0; vp < 2; ++vp) {
                const int v = vp * 2;
                float4 st = {r[2 * t][v],     r[2 * t + 1][v],
                             r[2 * t][v + 1], r[2 * t + 1][v + 1]};
                *(float4*)&p2[(size_t)c2 * PVOL + pb + v] = st;
            }
        }
    }
}

// ---------------------------------------------------------------------------
// qk: lane = voxel, 3 waves x 9 slots. All loads coalesced along vox.
// Writes a[27][vox] (softmaxed). Grid 216, block 192. LDS 6.75 KB.
// ---------------------------------------------------------------------------
__global__ __launch_bounds__(192) void qk_kernel(
    const float* __restrict__ qI, const float* __restrict__ kI,
    const float* __restrict__ biasW, float* __restrict__ aws)
{
    __shared__ float psh[27][64];
    const int tid  = threadIdx.x;
    const int lane = tid & 63;
    const int s0   = (tid >> 6) * 9;
    const int vox  = blockIdx.x * 64 + lane;
    const int pb   = pad_base(vox);

    int koff[9];
#pragma unroll
    for (int j = 0; j < 9; ++j) koff[j] = pb + slot_off(s0 + j);

    const float2* q2 = (const float2*)qI;
    const float2* k2 = (const float2*)kI;

    float ps[9] = {0.f, 0.f, 0.f, 0.f, 0.f, 0.f, 0.f, 0.f, 0.f};
    float qs = 0.f;
    for (int c2 = 0; c2 < NC2; ++c2) {
        const float2 q = q2[(size_t)c2 * NVOX + vox];
        qs += q.x + q.y;
        const size_t base = (size_t)c2 * PVOL;
#pragma unroll
        for (int j = 0; j < 9; ++j) {
            const float2 k = k2[base + koff[j]];
            ps[j] = fmaf(q.x, k.x, ps[j]);
            ps[j] = fmaf(q.y, k.y, ps[j]);
        }
    }
#pragma unroll
    for (int j = 0; j < 9; ++j)
        psh[s0 + j][lane] = fmaf(qs, biasW[s0 + j], ps[j]);
    __syncthreads();

    if (tid < 64) {
        float v[27];
        float mx = -1e30f;
#pragma unroll
        for (int s = 0; s < 27; ++s) { v[s] = psh[s][tid]; mx = fmaxf(mx, v[s]); }
        float sum = 0.f;
#pragma unroll
        for (int s = 0; s < 27; ++s) { v[s] = __expf(v[s] - mx); sum += v[s]; }
        const float inv = 1.f / sum;
        const int gv = blockIdx.x * 64 + tid;
#pragma unroll
        for (int s = 0; s < 27; ++s) aws[s * NVOX + gv] = v[s] * inv;
    }
}

// ---------------------------------------------------------------------------
// pv: lane = voxel, 4 waves x 16 channel-pairs. 27 coalesced float2 loads
// per c-pair (strong ILP). Output d_out[vox][c] fp32. Grid 216, block 256.
// ---------------------------------------------------------------------------
__global__ __launch_bounds__(256) void pv_kernel(
    const float* __restrict__ vI, const float* __restrict__ aws,
    float* __restrict__ out)
{
    const int tid  = threadIdx.x;
    const int lane = tid & 63;
    const int wv   = tid >> 6;          // 0..3
    const int vox  = blockIdx.x * 64 + lane;
    const int pb   = pad_base(vox);

    int voff[27];
#pragma unroll
    for (int s = 0; s < 27; ++s) voff[s] = pb + slot_off(s);

    float a[27];
#pragma unroll
    for (int s = 0; s < 27; ++s) a[s] = aws[s * NVOX + vox];

    const float2* v2 = (const float2*)vI;
    float* orow = out + (size_t)vox * CCH;

#pragma unroll
    for (int i = 0; i < 16; i += 2) {
        const int c2a = wv * 16 + i;
        float2 acc0 = {0.f, 0.f}, acc1 = {0.f, 0.f};
        const size_t ba = (size_t)c2a * PVOL;
        const size_t bb = ba + PVOL;
#pragma unroll
        for (int s = 0; s < 27; ++s) {
            const float2 va = v2[ba + voff[s]];
            const float2 vb = v2[bb + voff[s]];
            acc0.x = fmaf(a[s], va.x, acc0.x);
            acc0.y = fmaf(a[s], va.y, acc0.y);
            acc1.x = fmaf(a[s], vb.x, acc1.x);
            acc1.y = fmaf(a[s], vb.y, acc1.y);
        }
        float4 st = {acc0.x, acc0.y, acc1.x, acc1.y};
        *(float4*)(orow + c2a * 2) = st;       // c = 2*c2a .. 2*c2a+3
    }
}

// ---------------------------------------------------------------------------
extern "C" void kernel_launch(void* const* d_in, const int* in_sizes, int n_in,
                              void* d_out, int out_size, void* d_ws,
                              size_t ws_size, hipStream_t stream)
{
    const float* x    = (const float*)d_in[0];
    const float* wq   = (const float*)d_in[1];
    const float* bq   = (const float*)d_in[2];
    const float* wk   = (const float*)d_in[3];
    const float* bk   = (const float*)d_in[4];
    const float* wv   = (const float*)d_in[5];
    const float* bv   = (const float*)d_in[6];
    const float* relh = (const float*)d_in[7];
    const float* relw = (const float*)d_in[8];
    const float* reld = (const float*)d_in[9];

    float* qI    = (float*)d_ws;                        // 128*13824
    float* kI    = qI + (size_t)CCH * NVOX;             // 128*18928
    float* vI    = kI + (size_t)CCH * PVOL;             // 128*18928
    float* aws   = vI + (size_t)CCH * PVOL;             // 27*13824
    float* biasW = aws + (size_t)27 * NVOX;             // 27

    dim3 pgrid(NVOX / 64, 4);
    proj_kernel<<<pgrid, 256, 0, stream>>>(x, wq, bq, wk, bk, wv, bv,
                                           relh, relw, reld,
                                           qI, kI, vI, biasW);
    qk_kernel<<<NVOX / 64, 192, 0, stream>>>(qI, kI, biasW, aws);
    pv_kernel<<<NVOX / 64, 256, 0, stream>>>(vI, aws, (float*)d_out);
}

// Round 8
// 107.614 us; speedup vs baseline: 1.4963x; 1.4963x over previous
//
#include <hip/hip_runtime.h>
#include <hip/hip_fp16.h>

#define CCH 128
#define SV 24
#define NVOX 13824   // 24^3

typedef unsigned short u16;
typedef unsigned int   u32;

// unpack uint4 (8 packed fp16) -> 8 floats
__device__ __forceinline__ void cvt8h(uint4 r, float* f) {
    const __half2* h = (const __half2*)&r;
    const float2 a = __half22float2(h[0]);
    const float2 b = __half22float2(h[1]);
    const float2 c = __half22float2(h[2]);
    const float2 d = __half22float2(h[3]);
    f[0] = a.x; f[1] = a.y; f[2] = b.x; f[3] = b.y;
    f[4] = c.x; f[5] = c.y; f[6] = d.x; f[7] = d.y;
}
__device__ __forceinline__ u32 pack2h(float a, float b) {
    const __half2 h = __floats2half2_rn(a, b);
    return *(const u32*)&h;
}

// ---------------------------------------------------------------------------
// Projection GEMM: C[vox][o] = sum_c X[c][vox] * W[o][c] + b[o].
// One m in {q,k,v} per blockIdx.y. Block = 64 vox x 128 o, K-tile 32.
// LDS: Xs 8 KB + Ws 16 KB (transposed -> b128 compute reads, conflict-free;
// measured SQ_LDS_BANK_CONFLICT = 0 in the R5 run). Thread tile 4 vox x 8 o.
// q -> d_out fp32; k/v -> ws as packed fp16 rows + pad row (= bias) at NVOX.
// Grid (216, 3).
// ---------------------------------------------------------------------------
__global__ __launch_bounds__(256) void proj_kernel(
    const float* __restrict__ x,
    const float* __restrict__ wq, const float* __restrict__ bq,
    const float* __restrict__ wk, const float* __restrict__ bk,
    const float* __restrict__ wv, const float* __restrict__ bv,
    const float* __restrict__ relh, const float* __restrict__ relw,
    const float* __restrict__ reld,
    float* __restrict__ qout, u16* __restrict__ kws, u16* __restrict__ vws,
    float* __restrict__ biasW)
{
    const int m = blockIdx.y;                  // 0=q 1=k 2=v
    const float* __restrict__ w = (m == 0) ? wq : (m == 1) ? wk : wv;
    const float* __restrict__ b = (m == 0) ? bq : (m == 1) ? bk : bv;

    __shared__ float Xs[32][64];
    __shared__ float Ws[32][128];

    const int tid  = threadIdx.x;
    const int vox0 = blockIdx.x * 64;
    const int v0   = (tid & 15) * 4;           // compute: voxel group
    const int o0   = (tid >> 4) * 8;           // compute: output group

    // staging indices
    const int xc  = tid >> 3;                  // 0..31  (c-row)
    const int xv  = (tid & 7) * 4;             // 0,4,..,28
    const int wo  = tid >> 1;                  // 0..127 (o-row)
    const int wkh = (tid & 1) * 16;            // 0 or 16

    float acc[4][8] = {{0.f}};

    for (int k0 = 0; k0 < CCH; k0 += 32) {
        // X slice: 32 c-rows x 64 vox, coalesced (8 lanes cover 256B row)
        {
            const float* src = x + (size_t)(k0 + xc) * NVOX + vox0 + xv;
            const float4 a0 = *(const float4*)src;
            const float4 a1 = *(const float4*)(src + 32);
            *(float4*)&Xs[xc][xv]      = a0;
            *(float4*)&Xs[xc][xv + 32] = a1;
        }
        // W slice: rows [o][k0+wkh .. +15] -> transposed Ws[k][o]
        {
            const float* src = w + (size_t)wo * CCH + k0 + wkh;
            const float4 b0 = *(const float4*)src;
            const float4 b1 = *(const float4*)(src + 4);
            const float4 b2 = *(const float4*)(src + 8);
            const float4 b3 = *(const float4*)(src + 12);
            Ws[wkh + 0][wo] = b0.x;  Ws[wkh + 1][wo] = b0.y;
            Ws[wkh + 2][wo] = b0.z;  Ws[wkh + 3][wo] = b0.w;
            Ws[wkh + 4][wo] = b1.x;  Ws[wkh + 5][wo] = b1.y;
            Ws[wkh + 6][wo] = b1.z;  Ws[wkh + 7][wo] = b1.w;
            Ws[wkh + 8][wo] = b2.x;  Ws[wkh + 9][wo] = b2.y;
            Ws[wkh + 10][wo] = b2.z; Ws[wkh + 11][wo] = b2.w;
            Ws[wkh + 12][wo] = b3.x; Ws[wkh + 13][wo] = b3.y;
            Ws[wkh + 14][wo] = b3.z; Ws[wkh + 15][wo] = b3.w;
        }
        __syncthreads();

#pragma unroll
        for (int k = 0; k < 32; ++k) {
            const float4 xf = *(const float4*)&Xs[k][v0];
            const float4 w0 = *(const float4*)&Ws[k][o0];
            const float4 w1 = *(const float4*)&Ws[k][o0 + 4];
            const float xr[4] = {xf.x, xf.y, xf.z, xf.w};
            const float wr[8] = {w0.x, w0.y, w0.z, w0.w,
                                 w1.x, w1.y, w1.z, w1.w};
#pragma unroll
            for (int vv = 0; vv < 4; ++vv)
#pragma unroll
                for (int oo = 0; oo < 8; ++oo)
                    acc[vv][oo] = fmaf(xr[vv], wr[oo], acc[vv][oo]);
        }
        __syncthreads();
    }

    const float4 bf0 = *(const float4*)(b + o0);
    const float4 bf1 = *(const float4*)(b + o0 + 4);
    const float br[8] = {bf0.x, bf0.y, bf0.z, bf0.w,
                         bf1.x, bf1.y, bf1.z, bf1.w};

#pragma unroll
    for (int vv = 0; vv < 4; ++vv) {
        float r[8];
#pragma unroll
        for (int oo = 0; oo < 8; ++oo) r[oo] = acc[vv][oo] + br[oo];
        const size_t row = (size_t)(vox0 + v0 + vv) * CCH + o0;
        if (m == 0) {
            float4 s0 = {r[0], r[1], r[2], r[3]};
            float4 s1 = {r[4], r[5], r[6], r[7]};
            *(float4*)(qout + row) = s0;
            *(float4*)(qout + row + 4) = s1;
        } else {
            u16* out = (m == 1) ? kws : vws;
            uint4 st = {pack2h(r[0], r[1]), pack2h(r[2], r[3]),
                        pack2h(r[4], r[5]), pack2h(r[6], r[7])};
            *(uint4*)(out + row) = st;
        }
    }

    if (blockIdx.x == 0) {
        if (m == 1 && tid < CCH) {
            const __half hb = __float2half_rn(bk[tid]);
            kws[(size_t)NVOX * CCH + tid] = *(const u16*)&hb;
        }
        if (m == 2 && tid < CCH) {
            const __half hb = __float2half_rn(bv[tid]);
            vws[(size_t)NVOX * CCH + tid] = *(const u16*)&hb;
        }
        if (m == 1 && tid < 27) {
            const int i = tid / 9, j = (tid / 3) % 3, l = tid % 3;
            float s = 0.f;
            for (int c = 0; c < 64; ++c)
                s += relh[c * 3 + i] + relw[c * 3 + j] + reld[c * 3 + l];
            biasW[tid] = s;
        }
    }
}

// ---------------------------------------------------------------------------
// neighbor row offset for window slot s (folds at compile time after unroll)
// ---------------------------------------------------------------------------
__device__ __forceinline__ int nbr_off(int h, int w, int d, int s, int ch) {
    const int nh = h + s / 9 - 1;
    const int nw = w + (s / 3) % 3 - 1;
    const int nd = d + s % 3 - 1;
    const bool ok = ((unsigned)nh < (unsigned)SV) &&
                    ((unsigned)nw < (unsigned)SV) &&
                    ((unsigned)nd < (unsigned)SV);
    const int idx = ok ? ((nh * SV + nw) * SV + nd) : NVOX;
    return idx * CCH + ch;
}

// ---------------------------------------------------------------------------
// Attention: 16 lanes/voxel (8 ch each), 16 voxels per 256-thr block.
// q fp32 from d_out (overwritten in place); k/v fp16 gathers from ws in
// explicit batches of 9 uint4 loads for latency overlap. Grid 864.
// ---------------------------------------------------------------------------
__global__ __launch_bounds__(256) void attn_kernel(
    float* __restrict__ qo, const u16* __restrict__ kws,
    const u16* __restrict__ vws, const float* __restrict__ biasW)
{
    const int tid  = threadIdx.x;
    const int lane = tid & 15;
    const int vox  = blockIdx.x * 16 + (tid >> 4);
    const int h    = vox / 576;
    const int rem  = vox - h * 576;
    const int w    = rem / 24;
    const int d    = rem - w * 24;
    const int ch   = lane * 8;

    const float* qrow = qo + (size_t)vox * CCH + ch;
    const float4 q0 = *(const float4*)qrow;
    const float4 q1 = *(const float4*)(qrow + 4);
    const float qr[8] = {q0.x, q0.y, q0.z, q0.w, q1.x, q1.y, q1.z, q1.w};

    float qs = qr[0] + qr[1] + qr[2] + qr[3] + qr[4] + qr[5] + qr[6] + qr[7];
#pragma unroll
    for (int mm = 1; mm < 16; mm <<= 1) qs += __shfl_xor(qs, mm, 64);

    float ps[27];
    // ---- QK phase: 3 batches of 9 rows ----
#pragma unroll
    for (int sb = 0; sb < 27; sb += 9) {
        uint4 kf[9];
#pragma unroll
        for (int j = 0; j < 9; ++j)
            kf[j] = *(const uint4*)(kws + nbr_off(h, w, d, sb + j, ch));
#pragma unroll
        for (int j = 0; j < 9; ++j) {
            float f[8];
            cvt8h(kf[j], f);
            float p = qr[0] * f[0];
            p = fmaf(qr[1], f[1], p); p = fmaf(qr[2], f[2], p);
            p = fmaf(qr[3], f[3], p); p = fmaf(qr[4], f[4], p);
            p = fmaf(qr[5], f[5], p); p = fmaf(qr[6], f[6], p);
            p = fmaf(qr[7], f[7], p);
            ps[sb + j] = p;
        }
    }

#pragma unroll
    for (int mm = 1; mm < 16; mm <<= 1) {
#pragma unroll
        for (int s = 0; s < 27; ++s) ps[s] += __shfl_xor(ps[s], mm, 64);
    }

#pragma unroll
    for (int s = 0; s < 27; ++s) ps[s] = fmaf(qs, biasW[s], ps[s]);

    float mx = ps[0];
#pragma unroll
    for (int s = 1; s < 27; ++s) mx = fmaxf(mx, ps[s]);
    float sum = 0.f;
#pragma unroll
    for (int s = 0; s < 27; ++s) { ps[s] = __expf(ps[s] - mx); sum += ps[s]; }
    const float inv = 1.f / sum;
#pragma unroll
    for (int s = 0; s < 27; ++s) ps[s] *= inv;

    // ---- PV phase: 3 batches of 9 rows ----
    float o[8] = {0.f, 0.f, 0.f, 0.f, 0.f, 0.f, 0.f, 0.f};
#pragma unroll
    for (int sb = 0; sb < 27; sb += 9) {
        uint4 vf[9];
#pragma unroll
        for (int j = 0; j < 9; ++j)
            vf[j] = *(const uint4*)(vws + nbr_off(h, w, d, sb + j, ch));
#pragma unroll
        for (int j = 0; j < 9; ++j) {
            float f[8];
            cvt8h(vf[j], f);
            const float a = ps[sb + j];
#pragma unroll
            for (int e = 0; e < 8; ++e) o[e] = fmaf(a, f[e], o[e]);
        }
    }

    float* dst = qo + (size_t)vox * CCH + ch;
    float4 s0 = {o[0], o[1], o[2], o[3]};
    float4 s1 = {o[4], o[5], o[6], o[7]};
    *(float4*)dst = s0;
    *(float4*)(dst + 4) = s1;
}

// ---------------------------------------------------------------------------
extern "C" void kernel_launch(void* const* d_in, const int* in_sizes, int n_in,
                              void* d_out, int out_size, void* d_ws,
                              size_t ws_size, hipStream_t stream)
{
    const float* x    = (const float*)d_in[0];
    const float* wq   = (const float*)d_in[1];
    const float* bq   = (const float*)d_in[2];
    const float* wk   = (const float*)d_in[3];
    const float* bk   = (const float*)d_in[4];
    const float* wv   = (const float*)d_in[5];
    const float* bv   = (const float*)d_in[6];
    const float* relh = (const float*)d_in[7];
    const float* relw = (const float*)d_in[8];
    const float* reld = (const float*)d_in[9];

    u16*   kws   = (u16*)d_ws;                         // (NVOX+1)*128 fp16
    u16*   vws   = kws + (size_t)(NVOX + 1) * CCH;     // (NVOX+1)*128 fp16
    float* biasW = (float*)(vws + (size_t)(NVOX + 1) * CCH);  // 27 fp32

    dim3 pgrid(NVOX / 64, 3);
    proj_kernel<<<pgrid, 256, 0, stream>>>(x, wq, bq, wk, bk, wv, bv,
                                           relh, relw, reld,
                                           (float*)d_out, kws, vws, biasW);
    attn_kernel<<<NVOX / 16, 256, 0, stream>>>((float*)d_out, kws, vws, biasW);
}